// Round 5
// baseline (391.198 us; speedup 1.0000x reference)
//
#include <hip/hip_runtime.h>

#define NN 20000
#define NE 640000
#define CH 128
#define NG 64
#define NSLICE (NN / 8)
#define NBLK_CSR 512

typedef unsigned short u16;
typedef __attribute__((ext_vector_type(8))) short short8;   // 8 bf16 (4 VGPRs)
typedef __attribute__((ext_vector_type(4))) float floatx4;  // 4 fp32 acc

__device__ __forceinline__ float b2f(u16 u) {
    union { float f; unsigned int i; } v; v.i = ((unsigned int)u) << 16; return v.f;
}
__device__ __forceinline__ u16 f2b(float f) {
    unsigned int u = __float_as_uint(f);
    u += 0x7fff + ((u >> 16) & 1);          // RNE
    return (u16)(u >> 16);
}

// ---- convert x -> bf16; weights -> bf16 B-frag order; zero cnt/gsum/bar ----
// frag order: flat = (((ct*4+kc)*4+quad)*16+l16)*8+j ; value = W[k][n],
// n = ct*16+l16, k = kc*32+quad*8+j
#define ZWORDS (NN + NG * CH + 16)
__global__ __launch_bounds__(256) void cvt_all(const float* __restrict__ x, u16* __restrict__ xb,
                                               const float* __restrict__ W1a, const float* __restrict__ W1b,
                                               const float* __restrict__ W2a, const float* __restrict__ W2b,
                                               u16* __restrict__ wt, int* __restrict__ zbase) {
    int b = blockIdx.x;
    if (b < 2500) {                                   // x: 2.56M elems, 4/thread
        int idx = (b * 256 + threadIdx.x) * 4;
        float4 v = *(const float4*)(x + idx);
        ushort4 o = make_ushort4(f2b(v.x), f2b(v.y), f2b(v.z), f2b(v.w));
        *(ushort4*)(xb + idx) = o;
    } else if (b < 2756) {                            // weights: 4 x 16384 elems
        int wi = b - 2500;                            // 0..255
        int m = wi >> 6;
        int r = (wi & 63) * 256 + threadIdx.x;        // 0..16383
        int j = r & 7, l16 = (r >> 3) & 15, quad = (r >> 7) & 3;
        int kc = (r >> 9) & 3, ct = (r >> 11) & 7;
        int n = ct * 16 + l16, k = kc * 32 + quad * 8 + j;
        const float* W = (m == 0) ? W1a : (m == 1) ? W1b : (m == 2) ? W2a : W2b;
        wt[m * 16384 + r] = f2b(W[k * 128 + n]);
    } else {                                          // zero cnt + gsum + bar
        int idx = (b - 2756) * 256 + threadIdx.x;
        if (idx < ZWORDS) zbase[idx] = 0;
    }
}

// ---- fused CSR build: rank -> scan -> fill, one kernel, grid barriers -----
// 512 blocks x 256 thr = 2048 waves << 8192 capacity -> co-resident.
__device__ __forceinline__ void gridbar(int* bar, int slot) {
    __syncthreads();
    if (threadIdx.x == 0) {
        __threadfence();                               // agent-scope release (L2 writeback)
        atomicAdd(&bar[slot], 1);
        while (__hip_atomic_load(&bar[slot], __ATOMIC_ACQUIRE, __HIP_MEMORY_SCOPE_AGENT) < NBLK_CSR) {}
    }
    __syncthreads();
}

__global__ __launch_bounds__(256) void build_csr(const int* __restrict__ ei,
                                                 int* __restrict__ cnt, int* __restrict__ pk,
                                                 int* __restrict__ off, int* __restrict__ ssrc,
                                                 int* __restrict__ csum, int* __restrict__ coff,
                                                 int* __restrict__ bar) {
    int b = blockIdx.x, t = threadIdx.x;

    // phase 1: histogram + rank (packed dst | rank<<15)
    for (int k = t; k < 1250; k += 256) {
        int e = b * 1250 + k;
        int dst = ei[NE + e];
        unsigned r = atomicAdd(&cnt[dst], 1);
        pk[e] = dst | (int)(r << 15);
    }
    gridbar(bar, 0);

    // phase 2a: per-block chunk sums (40 nodes/block, blocks 0..499)
    if (b < 500) {
        if (t < 64) {
            int v = (t < 40) ? cnt[b * 40 + t] : 0;
            #pragma unroll
            for (int d = 32; d; d >>= 1) v += __shfl_xor(v, d);
            if (t == 0) csum[b] = v;
        }
    } else if (t == 0) csum[b] = 0;
    gridbar(bar, 1);

    // phase 2b: block 0 scans 512 chunk sums (wave 0, 8 elems/lane)
    if (b == 0 && t < 64) {
        int part[8], s = 0;
        #pragma unroll
        for (int i = 0; i < 8; ++i) { part[i] = csum[t * 8 + i]; s += part[i]; }
        int incl = s;
        for (int d = 1; d < 64; d <<= 1) { int v = __shfl_up(incl, d); if (t >= d) incl += v; }
        int run = incl - s;                            // exclusive
        #pragma unroll
        for (int i = 0; i < 8; ++i) { coff[t * 8 + i] = run; run += part[i]; }
    }
    gridbar(bar, 2);

    // phase 2c: per-block 40-node exclusive scan -> off
    if (b < 500 && t < 64) {
        int c = (t < 40) ? cnt[b * 40 + t] : 0;
        int incl = c;
        for (int d = 1; d < 64; d <<= 1) { int v = __shfl_up(incl, d); if (t >= d) incl += v; }
        if (t < 40) off[b * 40 + t] = coff[b] + incl - c;
    }
    if (b == 0 && t == 0) off[NN] = NE;
    gridbar(bar, 3);

    // phase 3: atomic-free XCD-sliced scatter (slice = b&7)
    int slice = b & 7, chunk = b >> 3;                 // 64 chunks x 10000 edges
    int lo = slice * NSLICE, hi = lo + NSLICE;
    int e0 = chunk * 10000, e1 = e0 + 10000;
    for (int e = e0 + t; e < e1; e += 256) {
        int p = pk[e];
        int dst = p & 32767;
        unsigned rank = ((unsigned)p) >> 15;
        if (dst >= lo && dst < hi)
            ssrc[off[dst] + rank] = ei[e];
    }
}

// ---- aggregate (bf16): out[n] = in[n] + sum_{e:dst==n} in[src[e]] ---------
// one wave/node: 4 edge-slots x 16 ch-groups (16B loads); unroll 4
__global__ __launch_bounds__(256) void agg_bf16(const u16* __restrict__ in, u16* __restrict__ out,
                                                const int* __restrict__ off, const int* __restrict__ ssrc) {
    int n = (blockIdx.x * 256 + threadIdx.x) >> 6;
    int lane = threadIdx.x & 63;
    int slot = lane >> 4, cg = lane & 15;
    int boff = cg * 8;
    float acc[8];
    if (slot == 0) {
        short8 v = *(const short8*)(in + (size_t)n * CH + boff);
        #pragma unroll
        for (int j = 0; j < 8; ++j) acc[j] = b2f((u16)v[j]);
    } else {
        #pragma unroll
        for (int j = 0; j < 8; ++j) acc[j] = 0.f;
    }
    int b = off[n], e = off[n + 1];
    int i = b + slot;
    for (; i + 12 < e; i += 16) {
        int s0 = ssrc[i], s1 = ssrc[i + 4], s2 = ssrc[i + 8], s3 = ssrc[i + 12];
        short8 v0 = *(const short8*)(in + (size_t)s0 * CH + boff);
        short8 v1 = *(const short8*)(in + (size_t)s1 * CH + boff);
        short8 v2 = *(const short8*)(in + (size_t)s2 * CH + boff);
        short8 v3 = *(const short8*)(in + (size_t)s3 * CH + boff);
        #pragma unroll
        for (int j = 0; j < 8; ++j)
            acc[j] += (b2f((u16)v0[j]) + b2f((u16)v1[j])) + (b2f((u16)v2[j]) + b2f((u16)v3[j]));
    }
    for (; i < e; i += 4) {
        int s0 = ssrc[i];
        short8 v0 = *(const short8*)(in + (size_t)s0 * CH + boff);
        #pragma unroll
        for (int j = 0; j < 8; ++j) acc[j] += b2f((u16)v0[j]);
    }
    #pragma unroll
    for (int j = 0; j < 8; ++j) {
        acc[j] += __shfl_xor(acc[j], 16);
        acc[j] += __shfl_xor(acc[j], 32);
    }
    if (slot == 0) {
        short8 o;
        #pragma unroll
        for (int j = 0; j < 8; ++j) o[j] = (short)f2b(acc[j]);
        *(short8*)(out + (size_t)n * CH + boff) = o;
    }
}

// ---- fused MLP (+ optional pool): relu( relu(A@Wa+ba) @ Wb + bb ) ---------
// 256 thr = 4 waves, 128 rows/block. H is wave-private (no barrier for GEMM path).
// do_pool: skip out-write; accumulate relu values into LDS gacc, flush to gsum.
__global__ __launch_bounds__(256) void mlp_fused(const u16* __restrict__ A,
                                                 const u16* __restrict__ wtA, const u16* __restrict__ wtB,
                                                 const float* __restrict__ biasA, const float* __restrict__ biasB,
                                                 u16* __restrict__ out,
                                                 const int* __restrict__ batch, float* __restrict__ gsum,
                                                 int do_pool) {
    __shared__ u16 H[128 * 136];
    __shared__ float gacc[NG * CH];                    // 32KB, used only when do_pool
    __shared__ int sgl[2];
    int t = threadIdx.x, wave = t >> 6, lane = t & 63;
    int quad = lane >> 4, l16 = lane & 15;
    int row0 = blockIdx.x * 128 + wave * 32;
    int rowblk = blockIdx.x * 128;

    int gg[2][4];                                      // graph id per owned row
    if (do_pool) {
        if (t == 0) {
            sgl[0] = batch[min(rowblk, NN - 1)];
            sgl[1] = batch[min(rowblk + 127, NN - 1)];
        }
        for (int i = t; i < NG * CH; i += 256) gacc[i] = 0.f;
        #pragma unroll
        for (int rt = 0; rt < 2; ++rt)
            #pragma unroll
            for (int r = 0; r < 4; ++r) {
                int row = row0 + rt * 16 + quad * 4 + r;
                gg[rt][r] = batch[min(row, NN - 1)];
            }
        __syncthreads();
    }

    short8 af[2][4];                                   // A[m=l16][k=quad*8+j]
    #pragma unroll
    for (int rt = 0; rt < 2; ++rt) {
        int r = row0 + rt * 16 + l16; if (r >= NN) r = NN - 1;
        #pragma unroll
        for (int kc = 0; kc < 4; ++kc)
            af[rt][kc] = *(const short8*)(A + (size_t)r * CH + kc * 32 + quad * 8);
    }

    #pragma unroll
    for (int ct = 0; ct < 8; ++ct) {
        floatx4 a0 = (floatx4)(0.f), a1 = (floatx4)(0.f);
        #pragma unroll
        for (int kc = 0; kc < 4; ++kc) {
            short8 bf = *(const short8*)(wtA + (((ct * 4 + kc) * 4 + quad) * 16 + l16) * 8);
            a0 = __builtin_amdgcn_mfma_f32_16x16x32_bf16(af[0][kc], bf, a0, 0, 0, 0);
            a1 = __builtin_amdgcn_mfma_f32_16x16x32_bf16(af[1][kc], bf, a1, 0, 0, 0);
        }
        float bv = biasA[ct * 16 + l16];
        #pragma unroll
        for (int r = 0; r < 4; ++r) {
            int lr0 = wave * 32 + 0 * 16 + quad * 4 + r;   // C/D: row=quad*4+r, col=l16
            int lr1 = wave * 32 + 1 * 16 + quad * 4 + r;
            H[lr0 * 136 + ct * 16 + l16] = f2b(fmaxf(a0[r] + bv, 0.f));
            H[lr1 * 136 + ct * 16 + l16] = f2b(fmaxf(a1[r] + bv, 0.f));
        }
    }

    short8 af2[2][4];                                   // wave-private H rows
    #pragma unroll
    for (int rt = 0; rt < 2; ++rt)
        #pragma unroll
        for (int kc = 0; kc < 4; ++kc)
            af2[rt][kc] = *(const short8*)&H[(wave * 32 + rt * 16 + l16) * 136 + kc * 32 + quad * 8];

    #pragma unroll
    for (int ct = 0; ct < 8; ++ct) {
        floatx4 a0 = (floatx4)(0.f), a1 = (floatx4)(0.f);
        #pragma unroll
        for (int kc = 0; kc < 4; ++kc) {
            short8 bf = *(const short8*)(wtB + (((ct * 4 + kc) * 4 + quad) * 16 + l16) * 8);
            a0 = __builtin_amdgcn_mfma_f32_16x16x32_bf16(af2[0][kc], bf, a0, 0, 0, 0);
            a1 = __builtin_amdgcn_mfma_f32_16x16x32_bf16(af2[1][kc], bf, a1, 0, 0, 0);
        }
        int col = ct * 16 + l16;
        float bv = biasB[col];
        #pragma unroll
        for (int rt = 0; rt < 2; ++rt) {
            floatx4 av = rt ? a1 : a0;
            #pragma unroll
            for (int r = 0; r < 4; ++r) {
                int row = row0 + rt * 16 + quad * 4 + r;
                if (row < NN) {
                    float v = fmaxf(av[r] + bv, 0.f);
                    if (do_pool) atomicAdd(&gacc[gg[rt][r] * CH + col], v);
                    else out[(size_t)row * CH + col] = f2b(v);
                }
            }
        }
    }

    if (do_pool) {
        __syncthreads();
        int glo = sgl[0], ghi = sgl[1];
        int span = (ghi - glo + 1) * CH;
        for (int i = t; i < span; i += 256)
            atomicAdd(&gsum[glo * CH + i], gacc[glo * CH + i]);
    }
}

// ---- final: out[g] = dot(gsum[g]/count_g, fcw) + fcb ----------------------
__global__ __launch_bounds__(128) void pool_final(const float* __restrict__ gsum, const int* __restrict__ batch,
                                                  const float* __restrict__ fcw, const float* __restrict__ fcb,
                                                  float* __restrict__ outp) {
    int g = blockIdx.x, t = threadIdx.x;
    __shared__ int se[2];
    if (t < 2) {
        int target = g + t, lo = 0, hi = NN;
        while (lo < hi) { int mid = (lo + hi) >> 1; if (batch[mid] < target) lo = mid + 1; else hi = mid; }
        se[t] = lo;
    }
    __syncthreads();
    int cnt = se[1] - se[0]; if (cnt < 1) cnt = 1;
    float v = gsum[g * CH + t] * fcw[t] / (float)cnt;
    __shared__ float red[128];
    red[t] = v; __syncthreads();
    for (int s = 64; s > 0; s >>= 1) { if (t < s) red[t] += red[t + s]; __syncthreads(); }
    if (t == 0) outp[g] = red[0] + fcb[0];
}

extern "C" void kernel_launch(void* const* d_in, const int* in_sizes, int n_in,
                              void* d_out, int out_size, void* d_ws, size_t ws_size,
                              hipStream_t stream) {
    const float* x   = (const float*)d_in[0];
    const int*   ei  = (const int*)d_in[1];
    const int* batch = (const int*)d_in[2];
    const float* W1a = (const float*)d_in[3];
    const float* b1a = (const float*)d_in[4];
    const float* W1b = (const float*)d_in[5];
    const float* b1b = (const float*)d_in[6];
    const float* W2a = (const float*)d_in[7];
    const float* b2a = (const float*)d_in[8];
    const float* W2b = (const float*)d_in[9];
    const float* b2b = (const float*)d_in[10];
    const float* fcw = (const float*)d_in[11];
    const float* fcb = (const float*)d_in[12];
    float* out = (float*)d_out;

    char* w = (char*)d_ws;
    u16* xb   = (u16*)w; w += (size_t)NN * CH * 2;
    u16* bufA = (u16*)w; w += (size_t)NN * CH * 2;
    u16* bufB = (u16*)w; w += (size_t)NN * CH * 2;
    u16* wt   = (u16*)w; w += (size_t)4 * 16384 * 2;
    int* cnt  = (int*)w; w += (size_t)NN * 4;        // ---- zero region start (ZWORDS)
    float* gsum = (float*)w; w += (size_t)NG * CH * 4;
    int* bar  = (int*)w; w += (size_t)16 * 4;        // ---- zero region end
    int* off  = (int*)w; w += (size_t)(NN + 4) * 4;
    int* csum = (int*)w; w += (size_t)NBLK_CSR * 4;
    int* coff = (int*)w; w += (size_t)NBLK_CSR * 4;
    int* pk   = (int*)w; w += (size_t)NE * 4;
    int* ssrc = (int*)w; w += (size_t)NE * 4;

    cvt_all<<<2867, 256, 0, stream>>>(x, xb, W1a, W1b, W2a, W2b, wt, cnt);
    build_csr<<<NBLK_CSR, 256, 0, stream>>>(ei, cnt, pk, off, ssrc, csum, coff, bar);

    // layer 1
    agg_bf16<<<5000, 256, 0, stream>>>(xb, bufA, off, ssrc);
    mlp_fused<<<157, 256, 0, stream>>>(bufA, wt + 0 * 16384, wt + 1 * 16384, b1a, b1b, bufB, batch, gsum, 0);
    // layer 2
    agg_bf16<<<5000, 256, 0, stream>>>(bufB, bufA, off, ssrc);
    mlp_fused<<<157, 256, 0, stream>>>(bufA, wt + 2 * 16384, wt + 3 * 16384, b2a, b2b, bufB, batch, gsum, 1);
    // final
    pool_final<<<NG, 128, 0, stream>>>(gsum, batch, fcw, fcb, out);
}

// Round 6
// 248.673 us; speedup vs baseline: 1.5731x; 1.5731x over previous
//
#include <hip/hip_runtime.h>

#define NN 20000
#define NE 640000
#define CH 128
#define NG 64
#define NSLICE (NN / 8)

typedef unsigned short u16;
typedef __attribute__((ext_vector_type(8))) short short8;   // 8 bf16 (4 VGPRs)
typedef __attribute__((ext_vector_type(4))) float floatx4;  // 4 fp32 acc

__device__ __forceinline__ float b2f(u16 u) {
    union { float f; unsigned int i; } v; v.i = ((unsigned int)u) << 16; return v.f;
}
__device__ __forceinline__ u16 f2b(float f) {
    unsigned int u = __float_as_uint(f);
    u += 0x7fff + ((u >> 16) & 1);          // RNE
    return (u16)(u >> 16);
}

// ---- prep: x->bf16, weights->B-frag order, zero gsum, CSR rank pass -------
// disjoint block ranges; cnt is pre-zeroed by an ordered memsetAsync, gsum is
// consumed only 4 kernels later, so no intra-kernel ordering is needed.
__global__ __launch_bounds__(256) void prep(const float* __restrict__ x, u16* __restrict__ xb,
                                            const float* __restrict__ W1a, const float* __restrict__ W1b,
                                            const float* __restrict__ W2a, const float* __restrict__ W2b,
                                            u16* __restrict__ wt, float* __restrict__ gsum,
                                            const int* __restrict__ ei,
                                            int* __restrict__ cnt, int* __restrict__ pk) {
    int b = blockIdx.x;
    if (b < 2500) {                                   // x: 2.56M elems, 4/thread
        int idx = (b * 256 + threadIdx.x) * 4;
        float4 v = *(const float4*)(x + idx);
        ushort4 o = make_ushort4(f2b(v.x), f2b(v.y), f2b(v.z), f2b(v.w));
        *(ushort4*)(xb + idx) = o;
    } else if (b < 2756) {                            // weights: 4 x 16384 elems
        int wi = b - 2500;                            // 0..255
        int m = wi >> 6;
        int r = (wi & 63) * 256 + threadIdx.x;        // 0..16383
        int j = r & 7, l16 = (r >> 3) & 15, quad = (r >> 7) & 3;
        int kc = (r >> 9) & 3, ct = (r >> 11) & 7;
        int n = ct * 16 + l16, k = kc * 32 + quad * 8 + j;
        const float* W = (m == 0) ? W1a : (m == 1) ? W1b : (m == 2) ? W2a : W2b;
        wt[m * 16384 + r] = f2b(W[k * 128 + n]);
    } else if (b < 2788) {                            // zero gsum (8192 floats)
        gsum[(b - 2756) * 256 + threadIdx.x] = 0.f;
    } else {                                          // CSR rank: 2500 blocks
        int e = (b - 2788) * 256 + threadIdx.x;
        if (e < NE) {
            int dst = ei[NE + e];
            unsigned r = atomicAdd((unsigned*)&cnt[dst], 1u);
            pk[e] = dst | (int)(r << 15);             // dst<32768, rank<2^17
        }
    }
}

// ---- scan cnt -> off ------------------------------------------------------
__global__ void scan_deg(const int* __restrict__ cnt, int* __restrict__ off) {
    __shared__ int psum[256];
    __shared__ int ex[256];
    int t = threadIdx.x;
    const int chunk = (NN + 255) / 256;
    int lo = t * chunk;
    int hi = lo + chunk; if (hi > NN) hi = NN; if (lo > NN) lo = NN;
    int s = 0;
    for (int i = lo; i < hi; ++i) s += cnt[i];
    psum[t] = s;
    __syncthreads();
    if (t == 0) {
        int run = 0;
        for (int i = 0; i < 256; ++i) { ex[i] = run; run += psum[i]; }
    }
    __syncthreads();
    int run = ex[t];
    for (int i = lo; i < hi; ++i) { off[i] = run; run += cnt[i]; }
    if (t == 0) off[NN] = NE;
}

// ---- CSR fill: atomic-free, XCD-sliced scatter ----------------------------
__global__ __launch_bounds__(256) void fill_sliced(const int* __restrict__ ei,
                                                   const int* __restrict__ off,
                                                   const int* __restrict__ pk,
                                                   int* __restrict__ ssrc) {
    int slice = blockIdx.x & 7;
    int chunk = blockIdx.x >> 3;                      // 0..127
    int lo = slice * NSLICE, hi = lo + NSLICE;
    int e0 = chunk * 5000, e1 = e0 + 5000;
    for (int e = e0 + threadIdx.x; e < e1; e += 256) {
        int p = pk[e];
        int dst = p & 32767;
        unsigned rank = ((unsigned)p) >> 15;
        if (dst >= lo && dst < hi)
            ssrc[off[dst] + rank] = ei[e];
    }
}

// ---- aggregate (bf16): out[n] = in[n] + sum_{e:dst==n} in[src[e]] ---------
// one wave/node: 4 edge-slots x 16 ch-groups (16B loads); unroll 4
__global__ __launch_bounds__(256) void agg_bf16(const u16* __restrict__ in, u16* __restrict__ out,
                                                const int* __restrict__ off, const int* __restrict__ ssrc) {
    int n = (blockIdx.x * 256 + threadIdx.x) >> 6;
    int lane = threadIdx.x & 63;
    int slot = lane >> 4, cg = lane & 15;
    int boff = cg * 8;
    float acc[8];
    if (slot == 0) {
        short8 v = *(const short8*)(in + (size_t)n * CH + boff);
        #pragma unroll
        for (int j = 0; j < 8; ++j) acc[j] = b2f((u16)v[j]);
    } else {
        #pragma unroll
        for (int j = 0; j < 8; ++j) acc[j] = 0.f;
    }
    int b = off[n], e = off[n + 1];
    int i = b + slot;
    for (; i + 12 < e; i += 16) {
        int s0 = ssrc[i], s1 = ssrc[i + 4], s2 = ssrc[i + 8], s3 = ssrc[i + 12];
        short8 v0 = *(const short8*)(in + (size_t)s0 * CH + boff);
        short8 v1 = *(const short8*)(in + (size_t)s1 * CH + boff);
        short8 v2 = *(const short8*)(in + (size_t)s2 * CH + boff);
        short8 v3 = *(const short8*)(in + (size_t)s3 * CH + boff);
        #pragma unroll
        for (int j = 0; j < 8; ++j)
            acc[j] += (b2f((u16)v0[j]) + b2f((u16)v1[j])) + (b2f((u16)v2[j]) + b2f((u16)v3[j]));
    }
    for (; i < e; i += 4) {
        int s0 = ssrc[i];
        short8 v0 = *(const short8*)(in + (size_t)s0 * CH + boff);
        #pragma unroll
        for (int j = 0; j < 8; ++j) acc[j] += b2f((u16)v0[j]);
    }
    #pragma unroll
    for (int j = 0; j < 8; ++j) {
        acc[j] += __shfl_xor(acc[j], 16);
        acc[j] += __shfl_xor(acc[j], 32);
    }
    if (slot == 0) {
        short8 o;
        #pragma unroll
        for (int j = 0; j < 8; ++j) o[j] = (short)f2b(acc[j]);
        *(short8*)(out + (size_t)n * CH + boff) = o;
    }
}

// ---- fused MLP (+ optional pool): relu( relu(A@Wa+ba) @ Wb + bb ) ---------
// 256 thr = 4 waves, 128 rows/block. H is wave-private (no barrier for GEMM path).
// do_pool: skip out-write; accumulate relu values into LDS gacc, flush to gsum.
__global__ __launch_bounds__(256) void mlp_fused(const u16* __restrict__ A,
                                                 const u16* __restrict__ wtA, const u16* __restrict__ wtB,
                                                 const float* __restrict__ biasA, const float* __restrict__ biasB,
                                                 u16* __restrict__ out,
                                                 const int* __restrict__ batch, float* __restrict__ gsum,
                                                 int do_pool) {
    __shared__ u16 H[128 * 136];
    __shared__ float gacc[NG * CH];                    // 32KB, used only when do_pool
    __shared__ int sgl[2];
    int t = threadIdx.x, wave = t >> 6, lane = t & 63;
    int quad = lane >> 4, l16 = lane & 15;
    int row0 = blockIdx.x * 128 + wave * 32;
    int rowblk = blockIdx.x * 128;

    int gg[2][4];                                      // graph id per owned row
    if (do_pool) {
        if (t == 0) {
            sgl[0] = batch[min(rowblk, NN - 1)];
            sgl[1] = batch[min(rowblk + 127, NN - 1)];
        }
        for (int i = t; i < NG * CH; i += 256) gacc[i] = 0.f;
        #pragma unroll
        for (int rt = 0; rt < 2; ++rt)
            #pragma unroll
            for (int r = 0; r < 4; ++r) {
                int row = row0 + rt * 16 + quad * 4 + r;
                gg[rt][r] = batch[min(row, NN - 1)];
            }
        __syncthreads();
    }

    short8 af[2][4];                                   // A[m=l16][k=quad*8+j]
    #pragma unroll
    for (int rt = 0; rt < 2; ++rt) {
        int r = row0 + rt * 16 + l16; if (r >= NN) r = NN - 1;
        #pragma unroll
        for (int kc = 0; kc < 4; ++kc)
            af[rt][kc] = *(const short8*)(A + (size_t)r * CH + kc * 32 + quad * 8);
    }

    #pragma unroll
    for (int ct = 0; ct < 8; ++ct) {
        floatx4 a0 = (floatx4)(0.f), a1 = (floatx4)(0.f);
        #pragma unroll
        for (int kc = 0; kc < 4; ++kc) {
            short8 bf = *(const short8*)(wtA + (((ct * 4 + kc) * 4 + quad) * 16 + l16) * 8);
            a0 = __builtin_amdgcn_mfma_f32_16x16x32_bf16(af[0][kc], bf, a0, 0, 0, 0);
            a1 = __builtin_amdgcn_mfma_f32_16x16x32_bf16(af[1][kc], bf, a1, 0, 0, 0);
        }
        float bv = biasA[ct * 16 + l16];
        #pragma unroll
        for (int r = 0; r < 4; ++r) {
            int lr0 = wave * 32 + 0 * 16 + quad * 4 + r;   // C/D: row=quad*4+r, col=l16
            int lr1 = wave * 32 + 1 * 16 + quad * 4 + r;
            H[lr0 * 136 + ct * 16 + l16] = f2b(fmaxf(a0[r] + bv, 0.f));
            H[lr1 * 136 + ct * 16 + l16] = f2b(fmaxf(a1[r] + bv, 0.f));
        }
    }

    short8 af2[2][4];                                   // wave-private H rows
    #pragma unroll
    for (int rt = 0; rt < 2; ++rt)
        #pragma unroll
        for (int kc = 0; kc < 4; ++kc)
            af2[rt][kc] = *(const short8*)&H[(wave * 32 + rt * 16 + l16) * 136 + kc * 32 + quad * 8];

    #pragma unroll
    for (int ct = 0; ct < 8; ++ct) {
        floatx4 a0 = (floatx4)(0.f), a1 = (floatx4)(0.f);
        #pragma unroll
        for (int kc = 0; kc < 4; ++kc) {
            short8 bf = *(const short8*)(wtB + (((ct * 4 + kc) * 4 + quad) * 16 + l16) * 8);
            a0 = __builtin_amdgcn_mfma_f32_16x16x32_bf16(af2[0][kc], bf, a0, 0, 0, 0);
            a1 = __builtin_amdgcn_mfma_f32_16x16x32_bf16(af2[1][kc], bf, a1, 0, 0, 0);
        }
        int col = ct * 16 + l16;
        float bv = biasB[col];
        #pragma unroll
        for (int rt = 0; rt < 2; ++rt) {
            floatx4 av = rt ? a1 : a0;
            #pragma unroll
            for (int r = 0; r < 4; ++r) {
                int row = row0 + rt * 16 + quad * 4 + r;
                if (row < NN) {
                    float v = fmaxf(av[r] + bv, 0.f);
                    if (do_pool) atomicAdd(&gacc[gg[rt][r] * CH + col], v);
                    else out[(size_t)row * CH + col] = f2b(v);
                }
            }
        }
    }

    if (do_pool) {
        __syncthreads();
        int glo = sgl[0], ghi = sgl[1];
        int span = (ghi - glo + 1) * CH;
        for (int i = t; i < span; i += 256)
            atomicAdd(&gsum[glo * CH + i], gacc[glo * CH + i]);
    }
}

// ---- final: out[g] = dot(gsum[g]/count_g, fcw) + fcb ----------------------
__global__ __launch_bounds__(128) void pool_final(const float* __restrict__ gsum, const int* __restrict__ batch,
                                                  const float* __restrict__ fcw, const float* __restrict__ fcb,
                                                  float* __restrict__ outp) {
    int g = blockIdx.x, t = threadIdx.x;
    __shared__ int se[2];
    if (t < 2) {
        int target = g + t, lo = 0, hi = NN;
        while (lo < hi) { int mid = (lo + hi) >> 1; if (batch[mid] < target) lo = mid + 1; else hi = mid; }
        se[t] = lo;
    }
    __syncthreads();
    int cnt = se[1] - se[0]; if (cnt < 1) cnt = 1;
    float v = gsum[g * CH + t] * fcw[t] / (float)cnt;
    __shared__ float red[128];
    red[t] = v; __syncthreads();
    for (int s = 64; s > 0; s >>= 1) { if (t < s) red[t] += red[t + s]; __syncthreads(); }
    if (t == 0) outp[g] = red[0] + fcb[0];
}

extern "C" void kernel_launch(void* const* d_in, const int* in_sizes, int n_in,
                              void* d_out, int out_size, void* d_ws, size_t ws_size,
                              hipStream_t stream) {
    const float* x   = (const float*)d_in[0];
    const int*   ei  = (const int*)d_in[1];
    const int* batch = (const int*)d_in[2];
    const float* W1a = (const float*)d_in[3];
    const float* b1a = (const float*)d_in[4];
    const float* W1b = (const float*)d_in[5];
    const float* b1b = (const float*)d_in[6];
    const float* W2a = (const float*)d_in[7];
    const float* b2a = (const float*)d_in[8];
    const float* W2b = (const float*)d_in[9];
    const float* b2b = (const float*)d_in[10];
    const float* fcw = (const float*)d_in[11];
    const float* fcb = (const float*)d_in[12];
    float* out = (float*)d_out;

    char* w = (char*)d_ws;
    u16* xb   = (u16*)w; w += (size_t)NN * CH * 2;
    u16* bufA = (u16*)w; w += (size_t)NN * CH * 2;
    u16* bufB = (u16*)w; w += (size_t)NN * CH * 2;
    u16* wt   = (u16*)w; w += (size_t)4 * 16384 * 2;
    int* cnt  = (int*)w; w += (size_t)NN * 4;
    float* gsum = (float*)w; w += (size_t)NG * CH * 4;
    int* off  = (int*)w; w += (size_t)(NN + 4) * 4;
    int* pk   = (int*)w; w += (size_t)NE * 4;
    int* ssrc = (int*)w; w += (size_t)NE * 4;

    hipMemsetAsync(cnt, 0, (size_t)NN * 4, stream);    // ordered before prep's rank pass

    prep<<<5288, 256, 0, stream>>>(x, xb, W1a, W1b, W2a, W2b, wt, gsum, ei, cnt, pk);
    scan_deg<<<1, 256, 0, stream>>>(cnt, off);
    fill_sliced<<<1024, 256, 0, stream>>>(ei, off, pk, ssrc);

    // layer 1
    agg_bf16<<<5000, 256, 0, stream>>>(xb, bufA, off, ssrc);
    mlp_fused<<<157, 256, 0, stream>>>(bufA, wt + 0 * 16384, wt + 1 * 16384, b1a, b1b, bufB, batch, gsum, 0);
    // layer 2
    agg_bf16<<<5000, 256, 0, stream>>>(bufB, bufA, off, ssrc);
    mlp_fused<<<157, 256, 0, stream>>>(bufA, wt + 2 * 16384, wt + 3 * 16384, b2a, b2b, bufB, batch, gsum, 1);
    // final
    pool_final<<<NG, 128, 0, stream>>>(gsum, batch, fcw, fcb, out);
}

// Round 7
// 231.929 us; speedup vs baseline: 1.6867x; 1.0722x over previous
//
#include <hip/hip_runtime.h>

#define NN 20000
#define NE 640000
#define CH 128
#define NG 64
#define NSLICE (NN / 8)
#define EPB 10000

typedef unsigned short u16;
typedef __attribute__((ext_vector_type(8))) short short8;   // 8 bf16 (4 VGPRs)
typedef __attribute__((ext_vector_type(4))) float floatx4;  // 4 fp32 acc

__device__ __forceinline__ float b2f(u16 u) {
    union { float f; unsigned int i; } v; v.i = ((unsigned int)u) << 16; return v.f;
}
__device__ __forceinline__ u16 f2b(float f) {
    unsigned int u = __float_as_uint(f);
    u += 0x7fff + ((u >> 16) & 1);          // RNE
    return (u16)(u >> 16);
}

// ---- prep: x->bf16, weights->B-frag order, zero gsum, CSR rank pass -------
__global__ __launch_bounds__(256) void prep(const float* __restrict__ x, u16* __restrict__ xb,
                                            const float* __restrict__ W1a, const float* __restrict__ W1b,
                                            const float* __restrict__ W2a, const float* __restrict__ W2b,
                                            u16* __restrict__ wt, float* __restrict__ gsum,
                                            const int* __restrict__ ei,
                                            int* __restrict__ cnt, int* __restrict__ pk) {
    int b = blockIdx.x;
    if (b < 2500) {                                   // x: 2.56M elems, 4/thread
        int idx = (b * 256 + threadIdx.x) * 4;
        float4 v = *(const float4*)(x + idx);
        ushort4 o = make_ushort4(f2b(v.x), f2b(v.y), f2b(v.z), f2b(v.w));
        *(ushort4*)(xb + idx) = o;
    } else if (b < 2756) {                            // weights: 4 x 16384 elems
        int wi = b - 2500;                            // 0..255
        int m = wi >> 6;
        int r = (wi & 63) * 256 + threadIdx.x;        // 0..16383
        int j = r & 7, l16 = (r >> 3) & 15, quad = (r >> 7) & 3;
        int kc = (r >> 9) & 3, ct = (r >> 11) & 7;
        int n = ct * 16 + l16, k = kc * 32 + quad * 8 + j;
        const float* W = (m == 0) ? W1a : (m == 1) ? W1b : (m == 2) ? W2a : W2b;
        wt[m * 16384 + r] = f2b(W[k * 128 + n]);
    } else if (b < 2788) {                            // zero gsum (8192 floats)
        gsum[(b - 2756) * 256 + threadIdx.x] = 0.f;
    } else {                                          // CSR rank: 2500 blocks
        int e = (b - 2788) * 256 + threadIdx.x;
        if (e < NE) {
            int dst = ei[NE + e];
            unsigned r = atomicAdd((unsigned*)&cnt[dst], 1u);
            pk[e] = dst | (int)(r << 15);             // dst<2^15, rank<2^17
        }
    }
}

// ---- fill2: per-block self-scan + atomic-free XCD-sliced scatter ----------
// 512 blocks = 8 slices x 64 chunks. Each block: base = sum cnt[0..lo)
// (coalesced), own-slice exclusive scan in LDS, chunk0 publishes off.
__global__ __launch_bounds__(256) void fill2(const int* __restrict__ ei,
                                             const int* __restrict__ cnt,
                                             const int* __restrict__ pk,
                                             int* __restrict__ off, int* __restrict__ ssrc) {
    __shared__ int loff[NSLICE];                      // 10KB: counts then off (absolute)
    __shared__ int red[256];
    __shared__ int wsum[4];
    int b = blockIdx.x, t = threadIdx.x;
    int slice = b & 7, chunk = b >> 3;
    int lo = slice * NSLICE, hi = lo + NSLICE;

    // base = sum cnt[0..lo)  (lo divisible by 4)
    const int4* c4 = (const int4*)cnt;
    int partial = 0;
    int npre4 = lo >> 2;
    for (int i = t; i < npre4; i += 256) {
        int4 v = c4[i];
        partial += v.x + v.y + v.z + v.w;
    }
    red[t] = partial;
    __syncthreads();
    for (int s = 128; s > 0; s >>= 1) { if (t < s) red[t] += red[t + s]; __syncthreads(); }
    int base = red[0];

    // stage own slice counts
    for (int i = t; i < NSLICE / 4; i += 256)
        *(int4*)&loff[i * 4] = c4[lo / 4 + i];
    __syncthreads();

    // exclusive scan over 2500: threads 0..249 own 10 each
    int tsum = 0;
    if (t < 250) {
        #pragma unroll
        for (int i = 0; i < 10; ++i) tsum += loff[t * 10 + i];
    }
    int lanev = t & 63, wv = t >> 6;
    int incl = tsum;
    for (int d = 1; d < 64; d <<= 1) { int xx = __shfl_up(incl, d); if (lanev >= d) incl += xx; }
    if (lanev == 63) wsum[wv] = incl;
    __syncthreads();                                   // all tsum reads done; wsum visible
    int wbase = 0;
    #pragma unroll
    for (int wp = 0; wp < 4; ++wp) wbase += (wp < wv) ? wsum[wp] : 0;
    int tex = base + wbase + incl - tsum;
    if (t < 250) {
        int run = tex;
        #pragma unroll
        for (int i = 0; i < 10; ++i) { int c = loff[t * 10 + i]; loff[t * 10 + i] = run; run += c; }
    }
    __syncthreads();

    if (chunk == 0) {                                  // publish off for agg
        for (int i = t; i < NSLICE; i += 256) off[lo + i] = loff[i];
        if (slice == 7 && t == 0) off[NN] = NE;
    }

    // scatter window
    int e0 = chunk * EPB, e1 = e0 + EPB;
    for (int e = e0 + t; e < e1; e += 256) {
        int p = pk[e];
        int dst = p & 32767;
        unsigned rank = ((unsigned)p) >> 15;
        if (dst >= lo && dst < hi)
            ssrc[loff[dst - lo] + rank] = ei[e];
    }
}

// ---- aggregate (bf16): out[n] = in[n] + sum_{e:dst==n} in[src[e]] ---------
// one wave/node: 4 slots x 16 ch-groups; 16-edge groups, predicated last group
// (no serial dependent tail).
__global__ __launch_bounds__(256) void agg_bf16(const u16* __restrict__ in, u16* __restrict__ out,
                                                const int* __restrict__ off, const int* __restrict__ ssrc) {
    int n = (blockIdx.x * 256 + threadIdx.x) >> 6;
    int lane = threadIdx.x & 63;
    int slot = lane >> 4, cg = lane & 15;
    int boff = cg * 8;
    float acc[8];
    if (slot == 0) {
        short8 v = *(const short8*)(in + (size_t)n * CH + boff);
        #pragma unroll
        for (int j = 0; j < 8; ++j) acc[j] = b2f((u16)v[j]);
    } else {
        #pragma unroll
        for (int j = 0; j < 8; ++j) acc[j] = 0.f;
    }
    int b = off[n], e = off[n + 1];
    int base = b;
    for (; base + 16 <= e; base += 16) {
        int i0 = base + slot;
        int s0 = ssrc[i0], s1 = ssrc[i0 + 4], s2 = ssrc[i0 + 8], s3 = ssrc[i0 + 12];
        short8 v0 = *(const short8*)(in + (size_t)s0 * CH + boff);
        short8 v1 = *(const short8*)(in + (size_t)s1 * CH + boff);
        short8 v2 = *(const short8*)(in + (size_t)s2 * CH + boff);
        short8 v3 = *(const short8*)(in + (size_t)s3 * CH + boff);
        #pragma unroll
        for (int j = 0; j < 8; ++j)
            acc[j] += (b2f((u16)v0[j]) + b2f((u16)v1[j])) + (b2f((u16)v2[j]) + b2f((u16)v3[j]));
    }
    if (base < e) {                                    // one predicated 16-group
        int i0 = base + slot;
        int idx[4]; bool ok[4];
        #pragma unroll
        for (int u = 0; u < 4; ++u) {
            int i = i0 + 4 * u;
            ok[u] = i < e;
            int s = ssrc[i];                           // ssrc padded by 16 ints
            idx[u] = ok[u] ? s : 0;                    // clamp to valid row
        }
        short8 v0 = *(const short8*)(in + (size_t)idx[0] * CH + boff);
        short8 v1 = *(const short8*)(in + (size_t)idx[1] * CH + boff);
        short8 v2 = *(const short8*)(in + (size_t)idx[2] * CH + boff);
        short8 v3 = *(const short8*)(in + (size_t)idx[3] * CH + boff);
        #pragma unroll
        for (int j = 0; j < 8; ++j) {
            float a0 = ok[0] ? b2f((u16)v0[j]) : 0.f;
            float a1 = ok[1] ? b2f((u16)v1[j]) : 0.f;
            float a2 = ok[2] ? b2f((u16)v2[j]) : 0.f;
            float a3 = ok[3] ? b2f((u16)v3[j]) : 0.f;
            acc[j] += (a0 + a1) + (a2 + a3);
        }
    }
    #pragma unroll
    for (int j = 0; j < 8; ++j) {
        acc[j] += __shfl_xor(acc[j], 16);
        acc[j] += __shfl_xor(acc[j], 32);
    }
    if (slot == 0) {
        short8 o;
        #pragma unroll
        for (int j = 0; j < 8; ++j) o[j] = (short)f2b(acc[j]);
        *(short8*)(out + (size_t)n * CH + boff) = o;
    }
}

// ---- fused MLP (+ optional pool), templated so mlp1 skips the 32KB gacc ---
template <int DO_POOL>
__global__ __launch_bounds__(256) void mlp_fused(const u16* __restrict__ A,
                                                 const u16* __restrict__ wtA, const u16* __restrict__ wtB,
                                                 const float* __restrict__ biasA, const float* __restrict__ biasB,
                                                 u16* __restrict__ out,
                                                 const int* __restrict__ batch, float* __restrict__ gsum) {
    __shared__ u16 H[128 * 136];
    __shared__ float gacc[DO_POOL ? NG * CH : 1];
    __shared__ int sgl[2];
    int t = threadIdx.x, wave = t >> 6, lane = t & 63;
    int quad = lane >> 4, l16 = lane & 15;
    int row0 = blockIdx.x * 128 + wave * 32;
    int rowblk = blockIdx.x * 128;

    int gg[2][4];
    if (DO_POOL) {
        if (t == 0) {
            sgl[0] = batch[min(rowblk, NN - 1)];
            sgl[1] = batch[min(rowblk + 127, NN - 1)];
        }
        for (int i = t; i < NG * CH; i += 256) gacc[i] = 0.f;
        #pragma unroll
        for (int rt = 0; rt < 2; ++rt)
            #pragma unroll
            for (int r = 0; r < 4; ++r) {
                int row = row0 + rt * 16 + quad * 4 + r;
                gg[rt][r] = batch[min(row, NN - 1)];
            }
        __syncthreads();
    }

    short8 af[2][4];                                   // A[m=l16][k=quad*8+j]
    #pragma unroll
    for (int rt = 0; rt < 2; ++rt) {
        int r = row0 + rt * 16 + l16; if (r >= NN) r = NN - 1;
        #pragma unroll
        for (int kc = 0; kc < 4; ++kc)
            af[rt][kc] = *(const short8*)(A + (size_t)r * CH + kc * 32 + quad * 8);
    }

    #pragma unroll
    for (int ct = 0; ct < 8; ++ct) {
        floatx4 a0 = (floatx4)(0.f), a1 = (floatx4)(0.f);
        #pragma unroll
        for (int kc = 0; kc < 4; ++kc) {
            short8 bf = *(const short8*)(wtA + (((ct * 4 + kc) * 4 + quad) * 16 + l16) * 8);
            a0 = __builtin_amdgcn_mfma_f32_16x16x32_bf16(af[0][kc], bf, a0, 0, 0, 0);
            a1 = __builtin_amdgcn_mfma_f32_16x16x32_bf16(af[1][kc], bf, a1, 0, 0, 0);
        }
        float bv = biasA[ct * 16 + l16];
        #pragma unroll
        for (int r = 0; r < 4; ++r) {
            int lr0 = wave * 32 + 0 * 16 + quad * 4 + r;   // C/D: row=quad*4+r, col=l16
            int lr1 = wave * 32 + 1 * 16 + quad * 4 + r;
            H[lr0 * 136 + ct * 16 + l16] = f2b(fmaxf(a0[r] + bv, 0.f));
            H[lr1 * 136 + ct * 16 + l16] = f2b(fmaxf(a1[r] + bv, 0.f));
        }
    }

    short8 af2[2][4];                                   // wave-private H rows
    #pragma unroll
    for (int rt = 0; rt < 2; ++rt)
        #pragma unroll
        for (int kc = 0; kc < 4; ++kc)
            af2[rt][kc] = *(const short8*)&H[(wave * 32 + rt * 16 + l16) * 136 + kc * 32 + quad * 8];

    #pragma unroll
    for (int ct = 0; ct < 8; ++ct) {
        floatx4 a0 = (floatx4)(0.f), a1 = (floatx4)(0.f);
        #pragma unroll
        for (int kc = 0; kc < 4; ++kc) {
            short8 bf = *(const short8*)(wtB + (((ct * 4 + kc) * 4 + quad) * 16 + l16) * 8);
            a0 = __builtin_amdgcn_mfma_f32_16x16x32_bf16(af2[0][kc], bf, a0, 0, 0, 0);
            a1 = __builtin_amdgcn_mfma_f32_16x16x32_bf16(af2[1][kc], bf, a1, 0, 0, 0);
        }
        int col = ct * 16 + l16;
        float bv = biasB[col];
        #pragma unroll
        for (int rt = 0; rt < 2; ++rt) {
            floatx4 av = rt ? a1 : a0;
            #pragma unroll
            for (int r = 0; r < 4; ++r) {
                int row = row0 + rt * 16 + quad * 4 + r;
                if (row < NN) {
                    float v = fmaxf(av[r] + bv, 0.f);
                    if (DO_POOL) atomicAdd(&gacc[gg[rt][r] * CH + col], v);
                    else out[(size_t)row * CH + col] = f2b(v);
                }
            }
        }
    }

    if (DO_POOL) {
        __syncthreads();
        int glo = sgl[0], ghi = sgl[1];
        int span = (ghi - glo + 1) * CH;
        for (int i = t; i < span; i += 256)
            atomicAdd(&gsum[glo * CH + i], gacc[glo * CH + i]);
    }
}

// ---- final: out[g] = dot(gsum[g]/count_g, fcw) + fcb ----------------------
__global__ __launch_bounds__(128) void pool_final(const float* __restrict__ gsum, const int* __restrict__ batch,
                                                  const float* __restrict__ fcw, const float* __restrict__ fcb,
                                                  float* __restrict__ outp) {
    int g = blockIdx.x, t = threadIdx.x;
    __shared__ int se[2];
    if (t < 2) {
        int target = g + t, lo = 0, hi = NN;
        while (lo < hi) { int mid = (lo + hi) >> 1; if (batch[mid] < target) lo = mid + 1; else hi = mid; }
        se[t] = lo;
    }
    __syncthreads();
    int cnt = se[1] - se[0]; if (cnt < 1) cnt = 1;
    float v = gsum[g * CH + t] * fcw[t] / (float)cnt;
    __shared__ float red[128];
    red[t] = v; __syncthreads();
    for (int s = 64; s > 0; s >>= 1) { if (t < s) red[t] += red[t + s]; __syncthreads(); }
    if (t == 0) outp[g] = red[0] + fcb[0];
}

extern "C" void kernel_launch(void* const* d_in, const int* in_sizes, int n_in,
                              void* d_out, int out_size, void* d_ws, size_t ws_size,
                              hipStream_t stream) {
    const float* x   = (const float*)d_in[0];
    const int*   ei  = (const int*)d_in[1];
    const int* batch = (const int*)d_in[2];
    const float* W1a = (const float*)d_in[3];
    const float* b1a = (const float*)d_in[4];
    const float* W1b = (const float*)d_in[5];
    const float* b1b = (const float*)d_in[6];
    const float* W2a = (const float*)d_in[7];
    const float* b2a = (const float*)d_in[8];
    const float* W2b = (const float*)d_in[9];
    const float* b2b = (const float*)d_in[10];
    const float* fcw = (const float*)d_in[11];
    const float* fcb = (const float*)d_in[12];
    float* out = (float*)d_out;

    char* w = (char*)d_ws;
    u16* xb   = (u16*)w; w += (size_t)NN * CH * 2;
    u16* bufA = (u16*)w; w += (size_t)NN * CH * 2;
    u16* bufB = (u16*)w; w += (size_t)NN * CH * 2;
    u16* wt   = (u16*)w; w += (size_t)4 * 16384 * 2;
    int* cnt  = (int*)w; w += (size_t)NN * 4;
    float* gsum = (float*)w; w += (size_t)NG * CH * 4;
    int* off  = (int*)w; w += (size_t)(NN + 4) * 4;
    int* pk   = (int*)w; w += (size_t)NE * 4;
    int* ssrc = (int*)w; w += (size_t)(NE + 16) * 4;   // +16 pad for predicated reads

    hipMemsetAsync(cnt, 0, (size_t)NN * 4, stream);    // ordered before prep's rank pass

    prep<<<5288, 256, 0, stream>>>(x, xb, W1a, W1b, W2a, W2b, wt, gsum, ei, cnt, pk);
    fill2<<<512, 256, 0, stream>>>(ei, cnt, pk, off, ssrc);

    // layer 1
    agg_bf16<<<5000, 256, 0, stream>>>(xb, bufA, off, ssrc);
    mlp_fused<0><<<157, 256, 0, stream>>>(bufA, wt + 0 * 16384, wt + 1 * 16384, b1a, b1b, bufB, batch, gsum);
    // layer 2
    agg_bf16<<<5000, 256, 0, stream>>>(bufB, bufA, off, ssrc);
    mlp_fused<1><<<157, 256, 0, stream>>>(bufA, wt + 2 * 16384, wt + 3 * 16384, b2a, b2b, bufB, batch, gsum);
    // final
    pool_final<<<NG, 128, 0, stream>>>(gsum, batch, fcw, fcb, out);
}